// Round 5
// baseline (4515.637 us; speedup 1.0000x reference)
//
#include <hip/hip_runtime.h>
#include <hip/hip_bf16.h>

#define NNODE 8192
#define DEG   32
#define DIN   256
#define EDIM  64
#define KC    576            // 2*DIN + EDIM
#define DD    512            // internal width D
#define NB    4              // nodes per block
#define MLOC  (NB*DEG)       // 128 edges per block
#define MEDGE (NNODE*DEG)
#define EXP   520            // 512 + 8 bf16 row pad
#define XDP   72             // 64 + 8 bf16 row pad (dst-chunk)

typedef __attribute__((ext_vector_type(8))) short short8;
typedef __attribute__((ext_vector_type(4))) short short4v;
typedef __attribute__((ext_vector_type(4))) float floatx4;
typedef __attribute__((ext_vector_type(4))) unsigned int uint4v;
typedef unsigned int u32;

__device__ __forceinline__ ushort f2bf(float f) {
  union { float f; unsigned int i; } v; v.f = f;
  return (ushort)((v.i + 0x7fffu + ((v.i >> 16) & 1u)) >> 16);
}
__device__ __forceinline__ u32 pk2(float a, float b) {
  return (u32)f2bf(a) | ((u32)f2bf(b) << 16);
}
__device__ __forceinline__ float gelu_f(float z) {
  return 0.5f * z * (1.0f + erff(z * 0.70710678118654752f));
}
__device__ __forceinline__ floatx4 zero4() { floatx4 v = {0.f, 0.f, 0.f, 0.f}; return v; }

__device__ __forceinline__ short8 ld_cvt8(const float* __restrict__ p) {
  floatx4 a = *(const floatx4*)(p);
  floatx4 b = *(const floatx4*)(p + 4);
  short8 r;
  r[0] = (short)f2bf(a[0]); r[1] = (short)f2bf(a[1]);
  r[2] = (short)f2bf(a[2]); r[3] = (short)f2bf(a[3]);
  r[4] = (short)f2bf(b[0]); r[5] = (short)f2bf(b[1]);
  r[6] = (short)f2bf(b[2]); r[7] = (short)f2bf(b[3]);
  return r;
}

#define MFMA16(a, b, c) __builtin_amdgcn_mfma_f32_16x16x32_bf16((a), (b), (c), 0, 0, 0)

// D-layout -> A/B-frag-layout in-register transform (verified r2-r4).
__device__ __forceinline__ u32 bpsel(int a, u32 v0, u32 v1, bool hi) {
  u32 x0 = (u32)__builtin_amdgcn_ds_bpermute(a, (int)v0);
  u32 x1 = (u32)__builtin_amdgcn_ds_bpermute(a, (int)v1);
  return hi ? x1 : x0;
}
__device__ __forceinline__ short8 frag4(int a0, int a1, bool hi,
                                        u32 t00, u32 t01, u32 t10, u32 t11) {
  uint4v r;
  r[0] = bpsel(a0, t00, t10, hi);
  r[1] = bpsel(a0, t01, t11, hi);
  r[2] = bpsel(a1, t00, t10, hi);
  r[3] = bpsel(a1, t01, t11, hi);
  union { uint4v u; short8 s; } c; c.u = r; return c.s;
}

__global__ __launch_bounds__(512, 2) void nt_fused(
    const float* __restrict__ x,  const float* __restrict__ ea,
    const int*   __restrict__ e,
    const ushort* __restrict__ Wc, const float* __restrict__ bc,
    const ushort* __restrict__ Wi, const float* __restrict__ bi,
    const ushort* __restrict__ Wo, const float* __restrict__ bo,
    float* __restrict__ out)
{
  __shared__ __align__(16) ushort sBUF[MLOC * EXP];  // ex, later attn-out (overlay)
  __shared__ __align__(16) ushort sXD [MLOC * XDP];  // x[dst] 64-col staging chunk

  const int m0  = blockIdx.x * MLOC;
  const int tid = threadIdx.x;
  const int w   = tid >> 6;    // wave 0..7 : head w / col slice w*64
  const int l   = tid & 63;
  const int lr  = l & 15;
  const int lg  = l >> 4;

  // ---- staging thread map (x[dst] chunks): 4 threads/row, 16 cols each
  const int srow = tid >> 2;
  const int scol = (tid & 3) * 16;
  const int sdst = e[MEDGE + m0 + srow];
  const float* sxp = x + (size_t)sdst * DIN;

  // ============ GEMM1: ex = gelu(gelu(feat @ Wc^T + bc)) -> sBUF =============
  {
    floatx4 acc[8][4];
    #pragma unroll
    for (int mt = 0; mt < 8; ++mt)
      #pragma unroll
      for (int nt = 0; nt < 4; ++nt) acc[mt][nt] = zero4();

    // --- k 0..255 : x[src] (all 32 rows of a node identical -> broadcast A)
    const float* xsrc[NB];
    #pragma unroll
    for (int nn = 0; nn < NB; ++nn) xsrc[nn] = x + (size_t)e[m0 + nn * DEG] * DIN;
    for (int s = 0; s < 8; ++s) {
      short8 bfr[4];
      #pragma unroll
      for (int nt = 0; nt < 4; ++nt)
        bfr[nt] = *(const short8*)(Wc + (size_t)(w * 64 + nt * 16 + lr) * KC + s * 32 + lg * 8);
      #pragma unroll
      for (int nn = 0; nn < NB; ++nn) {
        short8 af = ld_cvt8(xsrc[nn] + s * 32 + lg * 8);
        #pragma unroll
        for (int nt = 0; nt < 4; ++nt)
          acc[2 * nn][nt] = MFMA16(af, bfr[nt], acc[2 * nn][nt]);
      }
    }
    #pragma unroll
    for (int nn = 0; nn < NB; ++nn)
      #pragma unroll
      for (int nt = 0; nt < 4; ++nt) acc[2 * nn + 1][nt] = acc[2 * nn][nt];

    // --- k 256..511 : x[dst], staged via sXD in 4 chunks of 64 cols
    for (int c = 0; c < 4; ++c) {
      __syncthreads();   // previous chunk fully consumed
      {
        const float* sp = sxp + c * 64 + scol;
        floatx4 f0 = *(const floatx4*)(sp);
        floatx4 f1 = *(const floatx4*)(sp + 4);
        floatx4 f2 = *(const floatx4*)(sp + 8);
        floatx4 f3 = *(const floatx4*)(sp + 12);
        short8 p0, p1;
        #pragma unroll
        for (int j = 0; j < 4; ++j) {
          p0[j] = (short)f2bf(f0[j]); p0[4 + j] = (short)f2bf(f1[j]);
          p1[j] = (short)f2bf(f2[j]); p1[4 + j] = (short)f2bf(f3[j]);
        }
        *(short8*)(&sXD[srow * XDP + scol])     = p0;
        *(short8*)(&sXD[srow * XDP + scol + 8]) = p1;
      }
      __syncthreads();   // chunk staged
      for (int sl = 0; sl < 2; ++sl) {
        const int kk = 256 + c * 64 + sl * 32;
        short8 bfr[4];
        #pragma unroll
        for (int nt = 0; nt < 4; ++nt)
          bfr[nt] = *(const short8*)(Wc + (size_t)(w * 64 + nt * 16 + lr) * KC + kk + lg * 8);
        #pragma unroll
        for (int mt = 0; mt < 8; ++mt) {
          short8 af = *(const short8*)(&sXD[(mt * 16 + lr) * XDP + sl * 32 + lg * 8]);
          #pragma unroll
          for (int nt = 0; nt < 4; ++nt)
            acc[mt][nt] = MFMA16(af, bfr[nt], acc[mt][nt]);
        }
      }
    }

    // --- k 512..575 : edge_attr (direct)
    for (int s = 0; s < 2; ++s) {
      short8 bfr[4];
      #pragma unroll
      for (int nt = 0; nt < 4; ++nt)
        bfr[nt] = *(const short8*)(Wc + (size_t)(w * 64 + nt * 16 + lr) * KC + 512 + s * 32 + lg * 8);
      #pragma unroll
      for (int mt = 0; mt < 8; ++mt) {
        short8 af = ld_cvt8(ea + (size_t)(m0 + mt * 16 + lr) * EDIM + s * 32 + lg * 8);
        #pragma unroll
        for (int nt = 0; nt < 4; ++nt)
          acc[mt][nt] = MFMA16(af, bfr[nt], acc[mt][nt]);
      }
    }

    // --- epilogue -> sBUF
    #pragma unroll
    for (int nt = 0; nt < 4; ++nt) {
      const int col = w * 64 + nt * 16 + lr;
      const float bias = bc[col];
      #pragma unroll
      for (int mt = 0; mt < 8; ++mt)
        #pragma unroll
        for (int i = 0; i < 4; ++i)
          sBUF[(mt * 16 + lg * 4 + i) * EXP + col] = f2bf(gelu_f(gelu_f(acc[mt][nt][i] + bias)));
    }
  }
  __syncthreads();   // sBUF = ex complete

  // ============ attention, head w ============================================
  const int qb = w * 64, kb = 512 + w * 64, vb = 1024 + w * 64;
  const int pa0 = ((2 * (lg & 1)) * 16 + lr) * 4;
  const int pa1 = pa0 + 64;
  const bool hi = ((lg >> 1) & 1) != 0;

  u32 qpk[4][8][2], kpk[4][8][2];

  // ---- Q' and K' transposed passes, split by mt-half to bound registers
  #pragma unroll
  for (int qk = 0; qk < 2; ++qk) {
    const int rb = qk ? kb : qb;
    #pragma unroll
    for (int mh = 0; mh < 2; ++mh) {
      floatx4 acc2[2][8];
      #pragma unroll
      for (int m2 = 0; m2 < 2; ++m2)
        #pragma unroll
        for (int et = 0; et < 8; ++et) acc2[m2][et] = zero4();
      for (int ks = 0; ks < 16; ++ks) {
        short8 w0 = *(const short8*)(Wi + (size_t)(rb + (mh * 2 + 0) * 16 + lr) * DD + ks * 32 + lg * 8);
        short8 w1 = *(const short8*)(Wi + (size_t)(rb + (mh * 2 + 1) * 16 + lr) * DD + ks * 32 + lg * 8);
        #pragma unroll
        for (int et = 0; et < 8; ++et) {
          short8 exf = *(const short8*)(&sBUF[(et * 16 + lr) * EXP + ks * 32 + lg * 8]);
          acc2[0][et] = MFMA16(w0, exf, acc2[0][et]);
          acc2[1][et] = MFMA16(w1, exf, acc2[1][et]);
        }
      }
      #pragma unroll
      for (int m2 = 0; m2 < 2; ++m2) {
        const int mt = mh * 2 + m2;
        float b0 = bi[rb + mt * 16 + lg * 4 + 0];
        float b1 = bi[rb + mt * 16 + lg * 4 + 1];
        float b2 = bi[rb + mt * 16 + lg * 4 + 2];
        float b3 = bi[rb + mt * 16 + lg * 4 + 3];
        #pragma unroll
        for (int et = 0; et < 8; ++et) {
          u32 lo = pk2(acc2[m2][et][0] + b0, acc2[m2][et][1] + b1);
          u32 hip = pk2(acc2[m2][et][2] + b2, acc2[m2][et][3] + b3);
          if (qk == 0) { qpk[mt][et][0] = lo; qpk[mt][et][1] = hip; }
          else         { kpk[mt][et][0] = lo; kpk[mt][et][1] = hip; }
        }
      }
    }
  }

  // ---- scores + softmax per node -> ppk
  u32 ppk[NB][2][2][2];
  #pragma unroll
  for (int n = 0; n < NB; ++n) {
    floatx4 sacc[2][2];
    #pragma unroll
    for (int a = 0; a < 2; ++a)
      #pragma unroll
      for (int b = 0; b < 2; ++b) sacc[a][b] = zero4();
    #pragma unroll
    for (int kt = 0; kt < 2; ++kt) {
      short8 afr0 = frag4(pa0, pa1, hi, kpk[2*kt][2*n][0],   kpk[2*kt][2*n][1],   kpk[2*kt+1][2*n][0],   kpk[2*kt+1][2*n][1]);
      short8 afr1 = frag4(pa0, pa1, hi, kpk[2*kt][2*n+1][0], kpk[2*kt][2*n+1][1], kpk[2*kt+1][2*n+1][0], kpk[2*kt+1][2*n+1][1]);
      short8 bfr0 = frag4(pa0, pa1, hi, qpk[2*kt][2*n][0],   qpk[2*kt][2*n][1],   qpk[2*kt+1][2*n][0],   qpk[2*kt+1][2*n][1]);
      short8 bfr1 = frag4(pa0, pa1, hi, qpk[2*kt][2*n+1][0], qpk[2*kt][2*n+1][1], qpk[2*kt+1][2*n+1][0], qpk[2*kt+1][2*n+1][1]);
      sacc[0][0] = MFMA16(afr0, bfr0, sacc[0][0]);
      sacc[0][1] = MFMA16(afr0, bfr1, sacc[0][1]);
      sacc[1][0] = MFMA16(afr1, bfr0, sacc[1][0]);
      sacc[1][1] = MFMA16(afr1, bfr1, sacc[1][1]);
    }
    #pragma unroll
    for (int nt = 0; nt < 2; ++nt) {
      float s[2][4];
      float mx = -1e30f;
      #pragma unroll
      for (int mt = 0; mt < 2; ++mt)
        #pragma unroll
        for (int i = 0; i < 4; ++i) {
          s[mt][i] = sacc[mt][nt][i] * 0.125f;
          mx = fmaxf(mx, s[mt][i]);
        }
      mx = fmaxf(mx, __shfl_xor(mx, 16));
      mx = fmaxf(mx, __shfl_xor(mx, 32));
      float sm = 0.f;
      #pragma unroll
      for (int mt = 0; mt < 2; ++mt)
        #pragma unroll
        for (int i = 0; i < 4; ++i) { s[mt][i] = expf(s[mt][i] - mx); sm += s[mt][i]; }
      sm += __shfl_xor(sm, 16);
      sm += __shfl_xor(sm, 32);
      const float inv = 1.0f / sm;
      #pragma unroll
      for (int mt = 0; mt < 2; ++mt) {
        ppk[n][mt][nt][0] = pk2(s[mt][0] * inv, s[mt][1] * inv);
        ppk[n][mt][nt][1] = pk2(s[mt][2] * inv, s[mt][3] * inv);
      }
    }
  }

  // ---- V pass (normal orientation), all 8 edge-tiles
  u32 vpk[8][4][2];
  {
    floatx4 vacc[8][4];
    #pragma unroll
    for (int et = 0; et < 8; ++et)
      #pragma unroll
      for (int nt = 0; nt < 4; ++nt) vacc[et][nt] = zero4();
    for (int ks = 0; ks < 16; ++ks) {
      short8 wv[4];
      #pragma unroll
      for (int nt = 0; nt < 4; ++nt)
        wv[nt] = *(const short8*)(Wi + (size_t)(vb + nt * 16 + lr) * DD + ks * 32 + lg * 8);
      #pragma unroll
      for (int et = 0; et < 8; ++et) {
        short8 exf = *(const short8*)(&sBUF[(et * 16 + lr) * EXP + ks * 32 + lg * 8]);
        #pragma unroll
        for (int nt = 0; nt < 4; ++nt)
          vacc[et][nt] = MFMA16(exf, wv[nt], vacc[et][nt]);
      }
    }
    #pragma unroll
    for (int nt = 0; nt < 4; ++nt) {
      const float bv = bi[vb + nt * 16 + lr];
      #pragma unroll
      for (int et = 0; et < 8; ++et) {
        vpk[et][nt][0] = pk2(vacc[et][nt][0] + bv, vacc[et][nt][1] + bv);
        vpk[et][nt][1] = pk2(vacc[et][nt][2] + bv, vacc[et][nt][3] + bv);
      }
    }
  }
  __syncthreads();   // all sBUF(ex) reads done; safe to overlay attn-out

  // ---- PV per node -> sBUF (overlay)
  #pragma unroll
  for (int n = 0; n < NB; ++n) {
    short8 paf[2], vbf[4];
    #pragma unroll
    for (int qt = 0; qt < 2; ++qt)
      paf[qt] = frag4(pa0, pa1, hi, ppk[n][0][qt][0], ppk[n][0][qt][1], ppk[n][1][qt][0], ppk[n][1][qt][1]);
    #pragma unroll
    for (int nt = 0; nt < 4; ++nt)
      vbf[nt] = frag4(pa0, pa1, hi, vpk[2*n][nt][0], vpk[2*n][nt][1], vpk[2*n+1][nt][0], vpk[2*n+1][nt][1]);
    #pragma unroll
    for (int qt = 0; qt < 2; ++qt)
      #pragma unroll
      for (int nt = 0; nt < 4; ++nt) {
        floatx4 o = MFMA16(paf[qt], vbf[nt], zero4());
        #pragma unroll
        for (int i = 0; i < 4; ++i)
          sBUF[(n * 32 + qt * 16 + lg * 4 + i) * EXP + w * 64 + nt * 16 + lr] = f2bf(o[i]);
      }
  }
  __syncthreads();   // sBUF = attn-out complete

  // ============ GEMM3: h = gelu(AO @ Wo^T + bo) + weighted-mean + scatter ====
  floatx4 h3[8][4];
  #pragma unroll
  for (int mt = 0; mt < 8; ++mt)
    #pragma unroll
    for (int nt = 0; nt < 4; ++nt) h3[mt][nt] = zero4();
  for (int ks = 0; ks < 16; ++ks) {
    short8 bfr[4];
    #pragma unroll
    for (int nt = 0; nt < 4; ++nt)
      bfr[nt] = *(const short8*)(Wo + (size_t)(w * 64 + nt * 16 + lr) * DD + ks * 32 + lg * 8);
    #pragma unroll
    for (int mt = 0; mt < 8; ++mt) {
      short8 af = *(const short8*)(&sBUF[(mt * 16 + lr) * EXP + ks * 32 + lg * 8]);
      #pragma unroll
      for (int nt = 0; nt < 4; ++nt)
        h3[mt][nt] = MFMA16(af, bfr[nt], h3[mt][nt]);
    }
  }
  #pragma unroll
  for (int nt = 0; nt < 4; ++nt) {
    const float bias = bo[w * 64 + nt * 16 + lr];
    #pragma unroll
    for (int mt = 0; mt < 8; ++mt)
      #pragma unroll
      for (int i = 0; i < 4; ++i)
        h3[mt][nt][i] = gelu_f(h3[mt][nt][i] + bias);
  }
  // logits (head w): mean over ch1 (nt tiles 2,3), reduce across lr lanes
  float lgA[8][4];
  #pragma unroll
  for (int mt = 0; mt < 8; ++mt)
    #pragma unroll
    for (int i = 0; i < 4; ++i) {
      float tA = h3[mt][2][i] + h3[mt][3][i];
      #pragma unroll
      for (int d2 = 1; d2 < 16; d2 <<= 1) tA += __shfl_xor(tA, d2);
      lgA[mt][i] = tA * (1.0f / 32.0f);
    }
  // alpha = softmax over each node's 32 edges (m-tile pairs)
  float eAv[8][4], iA[NB];
  #pragma unroll
  for (int n = 0; n < NB; ++n) {
    float mx = -1e30f;
    #pragma unroll
    for (int m2 = 0; m2 < 2; ++m2)
      #pragma unroll
      for (int i = 0; i < 4; ++i) mx = fmaxf(mx, lgA[2*n + m2][i]);
    mx = fmaxf(mx, __shfl_xor(mx, 16));
    mx = fmaxf(mx, __shfl_xor(mx, 32));
    float sA = 0.f;
    #pragma unroll
    for (int m2 = 0; m2 < 2; ++m2)
      #pragma unroll
      for (int i = 0; i < 4; ++i) {
        eAv[2*n + m2][i] = expf(lgA[2*n + m2][i] - mx);
        sA += eAv[2*n + m2][i];
      }
    sA += __shfl_xor(sA, 16);
    sA += __shfl_xor(sA, 32);
    iA[n] = 1.0f / sA;
  }
  // scatter: out[dst][w*32 + p] += h_ch0 * alpha
  #pragma unroll
  for (int mt = 0; mt < 8; ++mt)
    #pragma unroll
    for (int i = 0; i < 4; ++i) {
      const int r  = mt * 16 + lg * 4 + i;
      const int d1 = e[MEDGE + m0 + r];
      float* bp = out + (size_t)d1 * 256 + w * 32;
      const float aA = eAv[mt][i] * iA[mt >> 1];
      atomicAdd(bp + lr,      h3[mt][0][i] * aA);
      atomicAdd(bp + 16 + lr, h3[mt][1][i] * aA);
    }
}

// fp32 -> bf16 weight pre-convert (4 elems/thread)
__global__ __launch_bounds__(256) void cvt_w(const float* __restrict__ src,
                                             ushort* __restrict__ dst, int n4)
{
  const int i = blockIdx.x * 256 + threadIdx.x;
  if (i < n4) {
    floatx4 v = *(const floatx4*)(src + (size_t)i * 4);
    short4v r;
    #pragma unroll
    for (int j = 0; j < 4; ++j) r[j] = (short)f2bf(v[j]);
    *(short4v*)(dst + (size_t)i * 4) = r;
  }
}

// ws layout (bf16 elements)
#define WS_WC 0
#define WS_WI (WS_WC + 512*KC)
#define WS_WO (WS_WI + 1536*DD)

extern "C" void kernel_launch(void* const* d_in, const int* in_sizes, int n_in,
                              void* d_out, int out_size, void* d_ws, size_t ws_size,
                              hipStream_t stream)
{
  (void)in_sizes; (void)n_in; (void)ws_size;
  const float* x  = (const float*)d_in[0];
  const float* ea = (const float*)d_in[1];
  const int*   e  = (const int*)d_in[2];
  const float* Wc = (const float*)d_in[3];
  const float* bc = (const float*)d_in[4];
  const float* Wi = (const float*)d_in[5];
  const float* bi = (const float*)d_in[6];
  const float* Wo = (const float*)d_in[7];
  const float* bo = (const float*)d_in[8];

  ushort* wsb = (ushort*)d_ws;
  ushort* Wcb = wsb + WS_WC;
  ushort* Wib = wsb + WS_WI;
  ushort* Wob = wsb + WS_WO;

  cvt_w<<<dim3((512 * KC / 4 + 255) / 256), dim3(256), 0, stream>>>(Wc, Wcb, 512 * KC / 4);
  cvt_w<<<dim3((1536 * DD / 4 + 255) / 256), dim3(256), 0, stream>>>(Wi, Wib, 1536 * DD / 4);
  cvt_w<<<dim3((512 * DD / 4 + 255) / 256), dim3(256), 0, stream>>>(Wo, Wob, 512 * DD / 4);

  float* out = (float*)d_out;
  hipMemsetAsync(out, 0, (size_t)out_size * sizeof(float), stream);

  nt_fused<<<dim3(NNODE / NB), dim3(512), 0, stream>>>(x, ea, e, Wcb, bc, Wib, bi, Wob, bo, out);
}

// Round 6
// 3133.894 us; speedup vs baseline: 1.4409x; 1.4409x over previous
//
#include <hip/hip_runtime.h>
#include <hip/hip_bf16.h>

#define NNODE 8192
#define DEG   32
#define DIN   256
#define EDIM  64
#define KC    576            // 2*DIN + EDIM
#define DD    512            // internal width D
#define NB    2              // nodes per block
#define MLOC  (NB*DEG)       // 64 edges per block
#define MEDGE (NNODE*DEG)
#define EXP   520            // 512 + 8 bf16 row pad
#define XDP   72             // 64 + 8 bf16 row pad (dst-chunk)

typedef __attribute__((ext_vector_type(8))) short short8;
typedef __attribute__((ext_vector_type(4))) short short4v;
typedef __attribute__((ext_vector_type(4))) float floatx4;
typedef __attribute__((ext_vector_type(4))) unsigned int uint4v;
typedef unsigned int u32;

__device__ __forceinline__ ushort f2bf(float f) {
  union { float f; unsigned int i; } v; v.f = f;
  return (ushort)((v.i + 0x7fffu + ((v.i >> 16) & 1u)) >> 16);
}
__device__ __forceinline__ u32 pk2(float a, float b) {
  return (u32)f2bf(a) | ((u32)f2bf(b) << 16);
}
__device__ __forceinline__ float gelu_f(float z) {
  return 0.5f * z * (1.0f + erff(z * 0.70710678118654752f));
}
__device__ __forceinline__ floatx4 zero4() { floatx4 v = {0.f, 0.f, 0.f, 0.f}; return v; }

__device__ __forceinline__ short8 ld_cvt8(const float* __restrict__ p) {
  floatx4 a = *(const floatx4*)(p);
  floatx4 b = *(const floatx4*)(p + 4);
  short8 r;
  r[0] = (short)f2bf(a[0]); r[1] = (short)f2bf(a[1]);
  r[2] = (short)f2bf(a[2]); r[3] = (short)f2bf(a[3]);
  r[4] = (short)f2bf(b[0]); r[5] = (short)f2bf(b[1]);
  r[6] = (short)f2bf(b[2]); r[7] = (short)f2bf(b[3]);
  return r;
}

#define MFMA16(a, b, c) __builtin_amdgcn_mfma_f32_16x16x32_bf16((a), (b), (c), 0, 0, 0)

// D-layout -> A/B-frag-layout in-register transform (verified r2-r5).
__device__ __forceinline__ u32 bpsel(int a, u32 v0, u32 v1, bool hi) {
  u32 x0 = (u32)__builtin_amdgcn_ds_bpermute(a, (int)v0);
  u32 x1 = (u32)__builtin_amdgcn_ds_bpermute(a, (int)v1);
  return hi ? x1 : x0;
}
__device__ __forceinline__ short8 frag4(int a0, int a1, bool hi,
                                        u32 t00, u32 t01, u32 t10, u32 t11) {
  uint4v r;
  r[0] = bpsel(a0, t00, t10, hi);
  r[1] = bpsel(a0, t01, t11, hi);
  r[2] = bpsel(a1, t00, t10, hi);
  r[3] = bpsel(a1, t01, t11, hi);
  union { uint4v u; short8 s; } c; c.u = r; return c.s;
}

__global__ __launch_bounds__(256, 2) void nt_fused(
    const float* __restrict__ x,  const float* __restrict__ ea,
    const int*   __restrict__ e,
    const ushort* __restrict__ Wc, const float* __restrict__ bc,
    const ushort* __restrict__ Wi, const float* __restrict__ bi,
    const ushort* __restrict__ Wo, const float* __restrict__ bo,
    float* __restrict__ out)
{
  __shared__ __align__(16) ushort sBUF[MLOC * EXP];  // ex, later attn-out (overlay)
  __shared__ __align__(16) ushort sXD [MLOC * XDP];  // x[dst] 64-col staging chunk

  const int m0  = blockIdx.x * MLOC;
  const int tid = threadIdx.x;
  const int w   = tid >> 6;    // wave 0..3 : heads 2w,2w+1 / col slice w*128
  const int l   = tid & 63;
  const int lr  = l & 15;
  const int lg  = l >> 4;

  // staging map (x[dst] chunks): 4 threads/row, 16 cols each
  const int srow = tid >> 2;
  const int scol = (tid & 3) * 16;
  const int sdst = e[MEDGE + m0 + srow];
  const float* sxp = x + (size_t)sdst * DIN;

  const float* xsrc0 = x + (size_t)e[m0] * DIN;
  const float* xsrc1 = x + (size_t)e[m0 + DEG] * DIN;

  // ============ GEMM1: ex = gelu(gelu(feat @ Wc^T + bc)) -> sBUF =============
  // two passes of 64 cols each (4 nt tiles) to bound accumulator count
  for (int p = 0; p < 2; ++p) {
    const int cb = w * 128 + p * 64;
    floatx4 acc[4][4];
    #pragma unroll
    for (int mt = 0; mt < 4; ++mt)
      #pragma unroll
      for (int nt = 0; nt < 4; ++nt) acc[mt][nt] = zero4();

    // k 0..255 : x[src] (32 rows per node identical -> compute once per node)
    for (int s = 0; s < 8; ++s) {
      short8 bfr[4];
      #pragma unroll
      for (int nt = 0; nt < 4; ++nt)
        bfr[nt] = *(const short8*)(Wc + (size_t)(cb + nt * 16 + lr) * KC + s * 32 + lg * 8);
      short8 a0 = ld_cvt8(xsrc0 + s * 32 + lg * 8);
      short8 a1 = ld_cvt8(xsrc1 + s * 32 + lg * 8);
      #pragma unroll
      for (int nt = 0; nt < 4; ++nt) {
        acc[0][nt] = MFMA16(a0, bfr[nt], acc[0][nt]);
        acc[2][nt] = MFMA16(a1, bfr[nt], acc[2][nt]);
      }
    }
    #pragma unroll
    for (int nt = 0; nt < 4; ++nt) { acc[1][nt] = acc[0][nt]; acc[3][nt] = acc[2][nt]; }

    // k 256..511 : x[dst], staged via sXD in 4 chunks of 64 cols
    for (int c = 0; c < 4; ++c) {
      __syncthreads();   // previous chunk fully consumed
      {
        const float* sp = sxp + c * 64 + scol;
        floatx4 f0 = *(const floatx4*)(sp);
        floatx4 f1 = *(const floatx4*)(sp + 4);
        floatx4 f2 = *(const floatx4*)(sp + 8);
        floatx4 f3 = *(const floatx4*)(sp + 12);
        short8 p0, p1;
        #pragma unroll
        for (int j = 0; j < 4; ++j) {
          p0[j] = (short)f2bf(f0[j]); p0[4 + j] = (short)f2bf(f1[j]);
          p1[j] = (short)f2bf(f2[j]); p1[4 + j] = (short)f2bf(f3[j]);
        }
        *(short8*)(&sXD[srow * XDP + scol])     = p0;
        *(short8*)(&sXD[srow * XDP + scol + 8]) = p1;
      }
      __syncthreads();   // chunk staged
      for (int sl = 0; sl < 2; ++sl) {
        const int kk = 256 + c * 64 + sl * 32;
        short8 bfr[4];
        #pragma unroll
        for (int nt = 0; nt < 4; ++nt)
          bfr[nt] = *(const short8*)(Wc + (size_t)(cb + nt * 16 + lr) * KC + kk + lg * 8);
        #pragma unroll
        for (int mt = 0; mt < 4; ++mt) {
          short8 af = *(const short8*)(&sXD[(mt * 16 + lr) * XDP + sl * 32 + lg * 8]);
          #pragma unroll
          for (int nt = 0; nt < 4; ++nt)
            acc[mt][nt] = MFMA16(af, bfr[nt], acc[mt][nt]);
        }
      }
    }

    // k 512..575 : edge_attr (direct)
    for (int s = 0; s < 2; ++s) {
      short8 bfr[4];
      #pragma unroll
      for (int nt = 0; nt < 4; ++nt)
        bfr[nt] = *(const short8*)(Wc + (size_t)(cb + nt * 16 + lr) * KC + 512 + s * 32 + lg * 8);
      #pragma unroll
      for (int mt = 0; mt < 4; ++mt) {
        short8 af = ld_cvt8(ea + (size_t)(m0 + mt * 16 + lr) * EDIM + s * 32 + lg * 8);
        #pragma unroll
        for (int nt = 0; nt < 4; ++nt)
          acc[mt][nt] = MFMA16(af, bfr[nt], acc[mt][nt]);
      }
    }

    // epilogue -> sBUF
    #pragma unroll
    for (int nt = 0; nt < 4; ++nt) {
      const int col = cb + nt * 16 + lr;
      const float bias = bc[col];
      #pragma unroll
      for (int mt = 0; mt < 4; ++mt)
        #pragma unroll
        for (int i = 0; i < 4; ++i)
          sBUF[(mt * 16 + lg * 4 + i) * EXP + col] = f2bf(gelu_f(gelu_f(acc[mt][nt][i] + bias)));
    }
  }
  __syncthreads();   // sBUF = ex complete

  // ============ attention: wave w handles heads 2w, 2w+1 =====================
  const int pa0 = ((2 * (lg & 1)) * 16 + lr) * 4;
  const int pa1 = pa0 + 64;
  const bool hi = ((lg >> 1) & 1) != 0;

  u32 ppk[2][2][2][4];   // [hidx][node][ke-tile][2*qt+p]
  u32 vpk[2][4][4][2];   // [hidx][et][nt][p]

  #pragma unroll
  for (int hh = 0; hh < 2; ++hh) {
    const int h = 2 * w + hh;
    const int qb = h * 64, kb = 512 + h * 64, vb = 1024 + h * 64;

    // ---- Q' transposed pass (rows = q-cols, cols = edges)
    u32 qpk[4][4][2];
    {
      floatx4 qacc[4][4];
      #pragma unroll
      for (int mt = 0; mt < 4; ++mt)
        #pragma unroll
        for (int et = 0; et < 4; ++et) qacc[mt][et] = zero4();
      for (int ks = 0; ks < 16; ++ks) {
        short8 wq[4];
        #pragma unroll
        for (int mt = 0; mt < 4; ++mt)
          wq[mt] = *(const short8*)(Wi + (size_t)(qb + mt * 16 + lr) * DD + ks * 32 + lg * 8);
        #pragma unroll
        for (int et = 0; et < 4; ++et) {
          short8 exf = *(const short8*)(&sBUF[(et * 16 + lr) * EXP + ks * 32 + lg * 8]);
          #pragma unroll
          for (int mt = 0; mt < 4; ++mt)
            qacc[mt][et] = MFMA16(wq[mt], exf, qacc[mt][et]);
        }
      }
      #pragma unroll
      for (int mt = 0; mt < 4; ++mt) {
        float b0 = bi[qb + mt * 16 + lg * 4 + 0];
        float b1 = bi[qb + mt * 16 + lg * 4 + 1];
        float b2 = bi[qb + mt * 16 + lg * 4 + 2];
        float b3 = bi[qb + mt * 16 + lg * 4 + 3];
        #pragma unroll
        for (int et = 0; et < 4; ++et) {
          qpk[mt][et][0] = pk2(qacc[mt][et][0] + b0, qacc[mt][et][1] + b1);
          qpk[mt][et][1] = pk2(qacc[mt][et][2] + b2, qacc[mt][et][3] + b3);
        }
      }
    }

    // ---- K' transposed pass
    u32 kpk[4][4][2];
    {
      floatx4 kacc[4][4];
      #pragma unroll
      for (int mt = 0; mt < 4; ++mt)
        #pragma unroll
        for (int et = 0; et < 4; ++et) kacc[mt][et] = zero4();
      for (int ks = 0; ks < 16; ++ks) {
        short8 wk[4];
        #pragma unroll
        for (int mt = 0; mt < 4; ++mt)
          wk[mt] = *(const short8*)(Wi + (size_t)(kb + mt * 16 + lr) * DD + ks * 32 + lg * 8);
        #pragma unroll
        for (int et = 0; et < 4; ++et) {
          short8 exf = *(const short8*)(&sBUF[(et * 16 + lr) * EXP + ks * 32 + lg * 8]);
          #pragma unroll
          for (int mt = 0; mt < 4; ++mt)
            kacc[mt][et] = MFMA16(wk[mt], exf, kacc[mt][et]);
        }
      }
      #pragma unroll
      for (int mt = 0; mt < 4; ++mt) {
        float b0 = bi[kb + mt * 16 + lg * 4 + 0];
        float b1 = bi[kb + mt * 16 + lg * 4 + 1];
        float b2 = bi[kb + mt * 16 + lg * 4 + 2];
        float b3 = bi[kb + mt * 16 + lg * 4 + 3];
        #pragma unroll
        for (int et = 0; et < 4; ++et) {
          kpk[mt][et][0] = pk2(kacc[mt][et][0] + b0, kacc[mt][et][1] + b1);
          kpk[mt][et][1] = pk2(kacc[mt][et][2] + b2, kacc[mt][et][3] + b3);
        }
      }
    }

    // ---- scores + softmax per node
    #pragma unroll
    for (int n = 0; n < 2; ++n) {
      floatx4 sacc[2][2];
      #pragma unroll
      for (int a = 0; a < 2; ++a)
        #pragma unroll
        for (int b = 0; b < 2; ++b) sacc[a][b] = zero4();
      #pragma unroll
      for (int kt = 0; kt < 2; ++kt) {
        short8 afr0 = frag4(pa0, pa1, hi, kpk[2*kt][2*n][0],   kpk[2*kt][2*n][1],   kpk[2*kt+1][2*n][0],   kpk[2*kt+1][2*n][1]);
        short8 afr1 = frag4(pa0, pa1, hi, kpk[2*kt][2*n+1][0], kpk[2*kt][2*n+1][1], kpk[2*kt+1][2*n+1][0], kpk[2*kt+1][2*n+1][1]);
        short8 bfr0 = frag4(pa0, pa1, hi, qpk[2*kt][2*n][0],   qpk[2*kt][2*n][1],   qpk[2*kt+1][2*n][0],   qpk[2*kt+1][2*n][1]);
        short8 bfr1 = frag4(pa0, pa1, hi, qpk[2*kt][2*n+1][0], qpk[2*kt][2*n+1][1], qpk[2*kt+1][2*n+1][0], qpk[2*kt+1][2*n+1][1]);
        sacc[0][0] = MFMA16(afr0, bfr0, sacc[0][0]);
        sacc[0][1] = MFMA16(afr0, bfr1, sacc[0][1]);
        sacc[1][0] = MFMA16(afr1, bfr0, sacc[1][0]);
        sacc[1][1] = MFMA16(afr1, bfr1, sacc[1][1]);
      }
      #pragma unroll
      for (int nt = 0; nt < 2; ++nt) {
        float s[2][4];
        float mx = -1e30f;
        #pragma unroll
        for (int mt = 0; mt < 2; ++mt)
          #pragma unroll
          for (int i = 0; i < 4; ++i) {
            s[mt][i] = sacc[mt][nt][i] * 0.125f;
            mx = fmaxf(mx, s[mt][i]);
          }
        mx = fmaxf(mx, __shfl_xor(mx, 16));
        mx = fmaxf(mx, __shfl_xor(mx, 32));
        float sm = 0.f;
        #pragma unroll
        for (int mt = 0; mt < 2; ++mt)
          #pragma unroll
          for (int i = 0; i < 4; ++i) { s[mt][i] = expf(s[mt][i] - mx); sm += s[mt][i]; }
        sm += __shfl_xor(sm, 16);
        sm += __shfl_xor(sm, 32);
        const float inv = 1.0f / sm;
        #pragma unroll
        for (int mt = 0; mt < 2; ++mt) {
          ppk[hh][n][mt][2 * nt + 0] = pk2(s[mt][0] * inv, s[mt][1] * inv);
          ppk[hh][n][mt][2 * nt + 1] = pk2(s[mt][2] * inv, s[mt][3] * inv);
        }
      }
    }

    // ---- V pass (normal orientation)
    {
      floatx4 vacc[4][4];
      #pragma unroll
      for (int et = 0; et < 4; ++et)
        #pragma unroll
        for (int nt = 0; nt < 4; ++nt) vacc[et][nt] = zero4();
      for (int ks = 0; ks < 16; ++ks) {
        short8 wv[4];
        #pragma unroll
        for (int nt = 0; nt < 4; ++nt)
          wv[nt] = *(const short8*)(Wi + (size_t)(vb + nt * 16 + lr) * DD + ks * 32 + lg * 8);
        #pragma unroll
        for (int et = 0; et < 4; ++et) {
          short8 exf = *(const short8*)(&sBUF[(et * 16 + lr) * EXP + ks * 32 + lg * 8]);
          #pragma unroll
          for (int nt = 0; nt < 4; ++nt)
            vacc[et][nt] = MFMA16(exf, wv[nt], vacc[et][nt]);
        }
      }
      #pragma unroll
      for (int nt = 0; nt < 4; ++nt) {
        const float bv = bi[vb + nt * 16 + lr];
        #pragma unroll
        for (int et = 0; et < 4; ++et) {
          vpk[hh][et][nt][0] = pk2(vacc[et][nt][0] + bv, vacc[et][nt][1] + bv);
          vpk[hh][et][nt][1] = pk2(vacc[et][nt][2] + bv, vacc[et][nt][3] + bv);
        }
      }
    }
  }
  __syncthreads();   // all sBUF(ex) reads done; safe to overlay attn-out

  // ---- PV per (head, node) -> sBUF (overlay)
  #pragma unroll
  for (int hh = 0; hh < 2; ++hh) {
    #pragma unroll
    for (int n = 0; n < 2; ++n) {
      short8 paf[2], vbf[4];
      #pragma unroll
      for (int qt = 0; qt < 2; ++qt)
        paf[qt] = frag4(pa0, pa1, hi, ppk[hh][n][0][2*qt+0], ppk[hh][n][0][2*qt+1],
                                      ppk[hh][n][1][2*qt+0], ppk[hh][n][1][2*qt+1]);
      #pragma unroll
      for (int nt = 0; nt < 4; ++nt)
        vbf[nt] = frag4(pa0, pa1, hi, vpk[hh][2*n][nt][0], vpk[hh][2*n][nt][1],
                                      vpk[hh][2*n+1][nt][0], vpk[hh][2*n+1][nt][1]);
      #pragma unroll
      for (int qt = 0; qt < 2; ++qt)
        #pragma unroll
        for (int nt = 0; nt < 4; ++nt) {
          floatx4 o = MFMA16(paf[qt], vbf[nt], zero4());
          #pragma unroll
          for (int i = 0; i < 4; ++i)
            sBUF[(n * 32 + qt * 16 + lg * 4 + i) * EXP + (2 * w + hh) * 64 + nt * 16 + lr] = f2bf(o[i]);
        }
    }
  }
  __syncthreads();   // sBUF = attn-out complete

  // ============ GEMM3: h = gelu(AO @ Wo^T + bo) + weighted-mean + scatter ====
  // two passes of 64 cols; pass p covers head 2w+p exactly (nt 0,1=ch0; 2,3=ch1)
  for (int p = 0; p < 2; ++p) {
    const int cb = w * 128 + p * 64;
    floatx4 h3[4][4];
    #pragma unroll
    for (int mt = 0; mt < 4; ++mt)
      #pragma unroll
      for (int nt = 0; nt < 4; ++nt) h3[mt][nt] = zero4();
    for (int ks = 0; ks < 16; ++ks) {
      short8 bfr[4];
      #pragma unroll
      for (int nt = 0; nt < 4; ++nt)
        bfr[nt] = *(const short8*)(Wo + (size_t)(cb + nt * 16 + lr) * DD + ks * 32 + lg * 8);
      #pragma unroll
      for (int mt = 0; mt < 4; ++mt) {
        short8 af = *(const short8*)(&sBUF[(mt * 16 + lr) * EXP + ks * 32 + lg * 8]);
        #pragma unroll
        for (int nt = 0; nt < 4; ++nt)
          h3[mt][nt] = MFMA16(af, bfr[nt], h3[mt][nt]);
      }
    }
    #pragma unroll
    for (int nt = 0; nt < 4; ++nt) {
      const float bias = bo[cb + nt * 16 + lr];
      #pragma unroll
      for (int mt = 0; mt < 4; ++mt)
        #pragma unroll
        for (int i = 0; i < 4; ++i)
          h3[mt][nt][i] = gelu_f(h3[mt][nt][i] + bias);
    }
    // logits (head 2w+p) = mean over ch1 (nt 2,3), reduce across lr lanes
    float lgA[4][4];
    #pragma unroll
    for (int mt = 0; mt < 4; ++mt)
      #pragma unroll
      for (int i = 0; i < 4; ++i) {
        float tA = h3[mt][2][i] + h3[mt][3][i];
        #pragma unroll
        for (int d2 = 1; d2 < 16; d2 <<= 1) tA += __shfl_xor(tA, d2);
        lgA[mt][i] = tA * (1.0f / 32.0f);
      }
    // alpha = softmax over each node's 32 edges
    float eAv[4][4], iA[2];
    #pragma unroll
    for (int n = 0; n < 2; ++n) {
      float mx = -1e30f;
      #pragma unroll
      for (int m2 = 0; m2 < 2; ++m2)
        #pragma unroll
        for (int i = 0; i < 4; ++i) mx = fmaxf(mx, lgA[2*n + m2][i]);
      mx = fmaxf(mx, __shfl_xor(mx, 16));
      mx = fmaxf(mx, __shfl_xor(mx, 32));
      float sA = 0.f;
      #pragma unroll
      for (int m2 = 0; m2 < 2; ++m2)
        #pragma unroll
        for (int i = 0; i < 4; ++i) {
          eAv[2*n + m2][i] = expf(lgA[2*n + m2][i] - mx);
          sA += eAv[2*n + m2][i];
        }
      sA += __shfl_xor(sA, 16);
      sA += __shfl_xor(sA, 32);
      iA[n] = 1.0f / sA;
    }
    // scatter: out[dst][(2w+p)*32 + cp] += h_ch0 * alpha
    #pragma unroll
    for (int mt = 0; mt < 4; ++mt)
      #pragma unroll
      for (int i = 0; i < 4; ++i) {
        const int r  = mt * 16 + lg * 4 + i;
        const int d1 = e[MEDGE + m0 + r];
        float* bp = out + (size_t)d1 * 256 + (2 * w + p) * 32;
        const float aA = eAv[mt][i] * iA[mt >> 1];
        atomicAdd(bp + lr,      h3[mt][0][i] * aA);
        atomicAdd(bp + 16 + lr, h3[mt][1][i] * aA);
      }
  }
}

// fp32 -> bf16 weight pre-convert (4 elems/thread)
__global__ __launch_bounds__(256) void cvt_w(const float* __restrict__ src,
                                             ushort* __restrict__ dst, int n4)
{
  const int i = blockIdx.x * 256 + threadIdx.x;
  if (i < n4) {
    floatx4 v = *(const floatx4*)(src + (size_t)i * 4);
    short4v r;
    #pragma unroll
    for (int j = 0; j < 4; ++j) r[j] = (short)f2bf(v[j]);
    *(short4v*)(dst + (size_t)i * 4) = r;
  }
}

// ws layout (bf16 elements)
#define WS_WC 0
#define WS_WI (WS_WC + 512*KC)
#define WS_WO (WS_WI + 1536*DD)

extern "C" void kernel_launch(void* const* d_in, const int* in_sizes, int n_in,
                              void* d_out, int out_size, void* d_ws, size_t ws_size,
                              hipStream_t stream)
{
  (void)in_sizes; (void)n_in; (void)ws_size;
  const float* x  = (const float*)d_in[0];
  const float* ea = (const float*)d_in[1];
  const int*   e  = (const int*)d_in[2];
  const float* Wc = (const float*)d_in[3];
  const float* bc = (const float*)d_in[4];
  const float* Wi = (const float*)d_in[5];
  const float* bi = (const float*)d_in[6];
  const float* Wo = (const float*)d_in[7];
  const float* bo = (const float*)d_in[8];

  ushort* wsb = (ushort*)d_ws;
  ushort* Wcb = wsb + WS_WC;
  ushort* Wib = wsb + WS_WI;
  ushort* Wob = wsb + WS_WO;

  cvt_w<<<dim3((512 * KC / 4 + 255) / 256), dim3(256), 0, stream>>>(Wc, Wcb, 512 * KC / 4);
  cvt_w<<<dim3((1536 * DD / 4 + 255) / 256), dim3(256), 0, stream>>>(Wi, Wib, 1536 * DD / 4);
  cvt_w<<<dim3((512 * DD / 4 + 255) / 256), dim3(256), 0, stream>>>(Wo, Wob, 512 * DD / 4);

  float* out = (float*)d_out;
  hipMemsetAsync(out, 0, (size_t)out_size * sizeof(float), stream);

  nt_fused<<<dim3(NNODE / NB), dim3(256), 0, stream>>>(x, ea, e, Wcb, bc, Wib, bi, Wob, bo, out);
}